// Round 1
// baseline (23902.840 us; speedup 1.0000x reference)
//
#include <hip/hip_runtime.h>

#define B_ 32
#define S_ 512
#define H_ 1024
#define L_ 3
#define BH (B_*H_)   // 32768

typedef __attribute__((ext_vector_type(8))) short short8;
typedef __attribute__((ext_vector_type(4))) float f4;

__device__ __forceinline__ unsigned short f2bf(float f){
  unsigned int u = __float_as_uint(f);
  u += 0x7fffu + ((u >> 16) & 1u);   // RNE
  return (unsigned short)(u >> 16);
}
__device__ __forceinline__ float sigmoidf_(float x){
  return 1.0f / (1.0f + __expf(-x));
}

// ---------------- prep kernels (run once per call; ws is re-poisoned) -------

// WAt[l][n][k]: n in [0,2048) (z cols 0..1023, r cols 1024..2047), k in [0,2048)
// k<1024 -> input weight (Wx / Wr), k>=1024 -> state weight (Wz / Wh)
__global__ void prep_WA_kernel(const float* __restrict__ Wx, const float* __restrict__ Wz,
                               const float* __restrict__ Wr, const float* __restrict__ Wh,
                               unsigned short* __restrict__ WAt){
  size_t idx = (size_t)blockIdx.x * blockDim.x + threadIdx.x;  // 3*2048*2048 exact
  int k = (int)(idx & 2047);
  size_t r = idx >> 11;
  int n = (int)(r & 2047);
  int l = (int)(r >> 11);
  int col = n & 1023;
  const float* W = (k < 1024) ? ((n >= 1024) ? Wr : Wx) : ((n >= 1024) ? Wh : Wz);
  WAt[idx] = f2bf(W[((size_t)l * 1024 + (k & 1023)) * 1024 + col]);
}

// WBt[l][n][k]: n in [0,1024), k<1024 -> Wg, k>=1024 -> Whg
__global__ void prep_WB_kernel(const float* __restrict__ Wg, const float* __restrict__ Whg,
                               unsigned short* __restrict__ WBt){
  size_t idx = (size_t)blockIdx.x * blockDim.x + threadIdx.x;  // 3*1024*2048 exact
  int k = (int)(idx & 2047);
  size_t r = idx >> 11;
  int n = (int)(r & 1023);
  int l = (int)(r >> 10);
  const float* W = (k < 1024) ? Wg : Whg;
  WBt[idx] = f2bf(W[((size_t)l * 1024 + (k & 1023)) * 1024 + n]);
}

// WoutT[o][k] = Wout[k][o]
__global__ void prep_Wout_kernel(const float* __restrict__ Wout,
                                 unsigned short* __restrict__ WoutT){
  size_t idx = (size_t)blockIdx.x * blockDim.x + threadIdx.x;  // 1024*1024 exact
  int k = (int)(idx & 1023);
  int o = (int)(idx >> 10);
  WoutT[idx] = f2bf(Wout[(size_t)k * 1024 + o]);
}

// Xb[t][b][i] = bf16(x[b][t][i])
__global__ void prep_X_kernel(const float* __restrict__ x, unsigned short* __restrict__ Xb){
  size_t idx = (size_t)blockIdx.x * blockDim.x + threadIdx.x;  // 512*32*1024 exact
  int i = (int)(idx & 1023);
  int b = (int)((idx >> 10) & 31);
  int t = (int)(idx >> 15);
  Xb[idx] = f2bf(x[((size_t)b * S_ + t) * 1024 + i]);
}

// HTall[v] for v=0..2 <- h0[:,v,:]  (bf16 history + fp32 ring)
__global__ void prep_H0_kernel(const float* __restrict__ h0,
                               unsigned short* __restrict__ HTb, float* __restrict__ HTf){
  int idx = blockIdx.x * blockDim.x + threadIdx.x;  // 3*32*1024 exact
  int h = idx & 1023;
  int b = (idx >> 10) & 31;
  int v = idx >> 15;
  float val = h0[((size_t)b * L_ + v) * 1024 + h];
  HTb[idx] = f2bf(val);   // idx == v*BH + b*1024 + h
  HTf[idx] = val;         // ring slot v&7 == v for v<3
}

// ---------------- pipelined slot kernels -----------------------------------
// Slot schedule (stream order = sync):
//   even slot s: L2A(s/2), L1A(s/2+1), L0A(s/2+2)
//   odd  slot s: L2B(u),   L1B(u+1),   L0B(u+2),  u=(s-1)/2
// A phase: preact = [inp|s] @ WA  -> z=sig(+bz) (fp32), rs=bf16(sig(+br)*s)
// B phase: pre    = [inp|rs] @ WB -> h = z*s + (1-z)*tanh(pre+bg)

__global__ __launch_bounds__(128) void slotA_kernel(
    const unsigned short* __restrict__ WAt, const unsigned short* __restrict__ Xb,
    const unsigned short* __restrict__ h0b, const unsigned short* __restrict__ h1b,
    const unsigned short* __restrict__ HTb, const float* __restrict__ HTf,
    float* __restrict__ zbuf, unsigned short* __restrict__ rsb,
    const float* __restrict__ bz, const float* __restrict__ br,
    int t0, int t1, int t2){
  int layer = blockIdx.x >> 6;          // 64 blocks per layer, 32 cols each
  int slice = blockIdx.x & 63;
  int t = (layer == 0) ? t0 : (layer == 1) ? t1 : t2;
  if (t < 0 || t >= S_) return;
  int wave = threadIdx.x >> 6, lane = threadIdx.x & 63;
  int quad = lane >> 4, l15 = lane & 15;
  int nw = slice * 32 + wave * 16 + l15;   // [0,2048)
  int tm = t & 3;
  const unsigned short* inp =
      (layer == 0) ? Xb  + (size_t)t  * BH :
      (layer == 1) ? h0b + (size_t)tm * BH :
                     h1b + (size_t)tm * BH;
  int v = t + layer;                                    // s = HTall[v]
  const unsigned short* sb = HTb + (size_t)v * BH;
  const unsigned short* bcol = WAt + ((size_t)layer * 2048 + nw) * 2048;
  f4 acc0 = {0.f,0.f,0.f,0.f}, acc1 = {0.f,0.f,0.f,0.f};
  const int row0 = l15 * H_, row1 = (l15 + 16) * H_;
  #pragma unroll 4
  for (int kk = 0; kk < 64; ++kk){
    int kb = kk * 32 + quad * 8;
    const unsigned short* asrc = (kb < 1024) ? (inp + kb) : (sb + kb - 1024);
    short8 a0 = *(const short8*)(asrc + row0);
    short8 a1 = *(const short8*)(asrc + row1);
    short8 bv = *(const short8*)(bcol + kb);
    acc0 = __builtin_amdgcn_mfma_f32_16x16x32_bf16(a0, bv, acc0, 0, 0, 0);
    acc1 = __builtin_amdgcn_mfma_f32_16x16x32_bf16(a1, bv, acc1, 0, 0, 0);
  }
  float* zb = zbuf + ((size_t)layer * 4 + tm) * BH;
  unsigned short* rs = rsb + ((size_t)layer * 4 + tm) * BH;
  const float* sf = HTf + (size_t)(v & 7) * BH;
  if (nw < 1024){
    int n = nw;
    float bias = bz[layer * H_ + n];
    #pragma unroll
    for (int i = 0; i < 8; ++i){
      float av = (i < 4) ? acc0[i] : acc1[i & 3];
      int b = ((i >= 4) ? 16 : 0) + quad * 4 + (i & 3);
      zb[b * H_ + n] = sigmoidf_(av + bias);
    }
  } else {
    int n = nw - 1024;
    float bias = br[layer * H_ + n];
    #pragma unroll
    for (int i = 0; i < 8; ++i){
      float av = (i < 4) ? acc0[i] : acc1[i & 3];
      int b = ((i >= 4) ? 16 : 0) + quad * 4 + (i & 3);
      float r = sigmoidf_(av + bias);
      rs[b * H_ + n] = f2bf(r * sf[b * H_ + n]);
    }
  }
}

__global__ __launch_bounds__(128) void slotB_kernel(
    const unsigned short* __restrict__ WBt, const unsigned short* __restrict__ Xb,
    unsigned short* __restrict__ h0b, unsigned short* __restrict__ h1b,
    unsigned short* __restrict__ HTb, float* __restrict__ HTf,
    const float* __restrict__ zbuf, const unsigned short* __restrict__ rsb,
    const float* __restrict__ bg,
    int t0, int t1, int t2){
  int layer = blockIdx.x >> 5;          // 32 blocks per layer, 32 cols each
  int slice = blockIdx.x & 31;
  int t = (layer == 0) ? t0 : (layer == 1) ? t1 : t2;
  if (t < 0 || t >= S_) return;
  int wave = threadIdx.x >> 6, lane = threadIdx.x & 63;
  int quad = lane >> 4, l15 = lane & 15;
  int nw = slice * 32 + wave * 16 + l15;   // [0,1024)
  int tm = t & 3;
  const unsigned short* inp =
      (layer == 0) ? Xb  + (size_t)t  * BH :
      (layer == 1) ? h0b + (size_t)tm * BH :
                     h1b + (size_t)tm * BH;
  const unsigned short* rs = rsb + ((size_t)layer * 4 + tm) * BH;
  const unsigned short* bcol = WBt + ((size_t)layer * 1024 + nw) * 2048;
  f4 acc0 = {0.f,0.f,0.f,0.f}, acc1 = {0.f,0.f,0.f,0.f};
  const int row0 = l15 * H_, row1 = (l15 + 16) * H_;
  #pragma unroll 4
  for (int kk = 0; kk < 64; ++kk){
    int kb = kk * 32 + quad * 8;
    const unsigned short* asrc = (kb < 1024) ? (inp + kb) : (rs + kb - 1024);
    short8 a0 = *(const short8*)(asrc + row0);
    short8 a1 = *(const short8*)(asrc + row1);
    short8 bv = *(const short8*)(bcol + kb);
    acc0 = __builtin_amdgcn_mfma_f32_16x16x32_bf16(a0, bv, acc0, 0, 0, 0);
    acc1 = __builtin_amdgcn_mfma_f32_16x16x32_bf16(a1, bv, acc1, 0, 0, 0);
  }
  int v = t + layer;
  const float* zb = zbuf + ((size_t)layer * 4 + tm) * BH;
  const float* sf = HTf + (size_t)(v & 7) * BH;
  float bias = bg[layer * H_ + nw];
  #pragma unroll
  for (int i = 0; i < 8; ++i){
    float av = (i < 4) ? acc0[i] : acc1[i & 3];
    int b = ((i >= 4) ? 16 : 0) + quad * 4 + (i & 3);
    float g = tanhf(av + bias);
    float z = zb[b * H_ + nw];
    float h = z * sf[b * H_ + nw] + (1.f - z) * g;
    if (layer == 2){
      HTf[(size_t)((t + 3) & 7) * BH + b * H_ + nw] = h;
      HTb[(size_t)(t + 3) * BH + b * H_ + nw] = f2bf(h);
    } else if (layer == 0){
      h0b[(size_t)tm * BH + b * H_ + nw] = f2bf(h);
    } else {
      h1b[(size_t)tm * BH + b * H_ + nw] = f2bf(h);
    }
  }
}

// ---------------- epilogue: Y = HT @ Wout + bout ----------------------------
__global__ __launch_bounds__(256) void out_proj_kernel(
    const unsigned short* __restrict__ HTb, const unsigned short* __restrict__ WoutT,
    const float* __restrict__ bout, float* __restrict__ Y){
  int tstep = blockIdx.x >> 2;
  int nblk  = blockIdx.x & 3;
  int wave = threadIdx.x >> 6, lane = threadIdx.x & 63;
  int quad = lane >> 4, l15 = lane & 15;
  const unsigned short* A = HTb + (size_t)(tstep + 3) * BH;
  int nbase = nblk * 256 + wave * 64;
  f4 acc[2][4] = {};
  for (int kk = 0; kk < 32; ++kk){
    int kb = kk * 32 + quad * 8;
    short8 a0 = *(const short8*)(A + l15 * H_ + kb);
    short8 a1 = *(const short8*)(A + (l15 + 16) * H_ + kb);
    #pragma unroll
    for (int nt = 0; nt < 4; ++nt){
      int n = nbase + nt * 16 + l15;
      short8 bv = *(const short8*)(WoutT + (size_t)n * 1024 + kb);
      acc[0][nt] = __builtin_amdgcn_mfma_f32_16x16x32_bf16(a0, bv, acc[0][nt], 0, 0, 0);
      acc[1][nt] = __builtin_amdgcn_mfma_f32_16x16x32_bf16(a1, bv, acc[1][nt], 0, 0, 0);
    }
  }
  #pragma unroll
  for (int mt = 0; mt < 2; ++mt)
    #pragma unroll
    for (int nt = 0; nt < 4; ++nt)
      #pragma unroll
      for (int r = 0; r < 4; ++r){
        int b = mt * 16 + quad * 4 + r;
        int n = nbase + nt * 16 + l15;
        Y[(size_t)b * (S_ * 1024) + (size_t)tstep * 1024 + n] = acc[mt][nt][r] + bout[n];
      }
}

// hidden_state[b][l][h] = ht_{S-3+l}[b][h] = HTall[S+l]
__global__ void copy_hidden_kernel(const float* __restrict__ HTf, float* __restrict__ out2){
  int idx = blockIdx.x * blockDim.x + threadIdx.x;  // 3*32*1024 exact
  int h = idx & 1023;
  int b = (idx >> 10) & 31;
  int v = idx >> 15;
  out2[((size_t)b * L_ + v) * 1024 + h] = HTf[(size_t)((S_ + v) & 7) * BH + b * H_ + h];
}

// ---------------------------------------------------------------------------
extern "C" void kernel_launch(void* const* d_in, const int* in_sizes, int n_in,
                              void* d_out, int out_size, void* d_ws, size_t ws_size,
                              hipStream_t stream){
  (void)in_sizes; (void)n_in; (void)out_size;
  const float* x    = (const float*)d_in[0];
  const float* h0   = (const float*)d_in[1];
  const float* Wx   = (const float*)d_in[2];
  const float* Wz   = (const float*)d_in[3];
  const float* bz   = (const float*)d_in[4];
  const float* Wr   = (const float*)d_in[5];
  const float* Wh   = (const float*)d_in[6];
  const float* br   = (const float*)d_in[7];
  const float* Wg   = (const float*)d_in[8];
  const float* Whg  = (const float*)d_in[9];
  const float* bg   = (const float*)d_in[10];
  const float* Wout = (const float*)d_in[11];
  const float* bout = (const float*)d_in[12];
  float* out = (float*)d_out;

  char* p = (char*)d_ws;
  unsigned short* WAt   = (unsigned short*)p; p += (size_t)3 * 2048 * 2048 * 2;
  unsigned short* WBt   = (unsigned short*)p; p += (size_t)3 * 1024 * 2048 * 2;
  unsigned short* WoutT = (unsigned short*)p; p += (size_t)1024 * 1024 * 2;
  unsigned short* Xb    = (unsigned short*)p; p += (size_t)S_ * BH * 2;
  unsigned short* HTb   = (unsigned short*)p; p += (size_t)(S_ + 3) * BH * 2;
  float*          HTf   = (float*)p;          p += (size_t)8 * BH * 4;
  unsigned short* h0b   = (unsigned short*)p; p += (size_t)4 * BH * 2;
  unsigned short* h1b   = (unsigned short*)p; p += (size_t)4 * BH * 2;
  float*          zbuf  = (float*)p;          p += (size_t)3 * 4 * BH * 4;
  unsigned short* rsb   = (unsigned short*)p; p += (size_t)3 * 4 * BH * 2;
  if ((size_t)(p - (char*)d_ws) > ws_size) return;  // ws too small: bail (will fail loudly)

  prep_WA_kernel  <<<49152, 256, 0, stream>>>(Wx, Wz, Wr, Wh, WAt);
  prep_WB_kernel  <<<24576, 256, 0, stream>>>(Wg, Whg, WBt);
  prep_Wout_kernel<<< 4096, 256, 0, stream>>>(Wout, WoutT);
  prep_X_kernel   <<<65536, 256, 0, stream>>>(x, Xb);
  prep_H0_kernel  <<<  384, 256, 0, stream>>>(h0, HTb, HTf);

  for (int s = -4; s <= 2 * S_ - 1; ++s){
    if ((s & 1) == 0){
      int u = s / 2;                     // exact (s even), also for negatives
      slotA_kernel<<<192, 128, 0, stream>>>(WAt, Xb, h0b, h1b, HTb, HTf, zbuf, rsb,
                                            bz, br, u + 2, u + 1, u);
    } else {
      int u = (s - 1) / 2;               // exact (s-1 even)
      slotB_kernel<<<96, 128, 0, stream>>>(WBt, Xb, h0b, h1b, HTb, HTf, zbuf, rsb,
                                           bg, u + 2, u + 1, u);
    }
  }

  out_proj_kernel   <<<2048, 256, 0, stream>>>(HTb, WoutT, bout, out);
  copy_hidden_kernel<<< 384, 256, 0, stream>>>(HTf, out + (size_t)B_ * S_ * 1024);
}